// Round 3
// baseline (612.358 us; speedup 1.0000x reference)
//
#include <hip/hip_runtime.h>
#include <stdint.h>

#define T_LEN 4096
#define D_DIM 2560
#define NQ 8
#define NKV 4
#define HD 256
#define QKV_COLS 4096
#define ENC_COLS 2048
#define WIN 1024
#define NEG_BIG -3.0e38f

typedef __bf16 bf16x8 __attribute__((ext_vector_type(8)));
typedef short s16x8 __attribute__((ext_vector_type(8)));
typedef float f32x4 __attribute__((ext_vector_type(4)));

__device__ __forceinline__ float bf2f(ushort u) {
  union { unsigned u; float f; } v; v.u = ((unsigned)u) << 16; return v.f;
}
__device__ __forceinline__ ushort f2bf(float f) {
  union { float f; unsigned u; } v; v.f = f;
  unsigned r = v.u + 0x7fffu + ((v.u >> 16) & 1u);
  return (ushort)(r >> 16);
}
__device__ __forceinline__ bf16x8 as_bf(s16x8 s) {
  return __builtin_bit_cast(bf16x8, s);
}
__device__ __forceinline__ void async_load16(void* lds, const void* g) {
  __builtin_amdgcn_global_load_lds(
      (const __attribute__((address_space(1))) void*)g,
      (__attribute__((address_space(3))) void*)lds, 16, 0, 0);
}

// ---- dtype probe: bf16 N(0,1) never has exponent >= 192; fp32 low halves
// ---- read as bf16 hit that ~25% of the time. hdr[0]=mode, hdr[1]=0.
__global__ void detect_kernel(const ushort* __restrict__ x1, int* hdr) {
  __shared__ int cnt;
  if (threadIdx.x == 0) cnt = 0;
  __syncthreads();
  int c = 0;
#pragma unroll
  for (int i = 0; i < 8; i++) {
    ushort u = x1[threadIdx.x * 8 + i];
    c += (((u >> 7) & 0xFF) >= 192) ? 1 : 0;
  }
  atomicAdd(&cnt, c);
  __syncthreads();
  if (threadIdx.x == 0) {
    hdr[0] = (cnt > 32) ? 1 : 0;
    hdr[1] = 0;
  }
}

// ---- x1/x2 -> canonical bf16 X (4096 x 2560). 2560 blocks per half. ----
__global__ __launch_bounds__(256, 4) void convert_x_kernel(
    const void* __restrict__ x1, const void* __restrict__ x2,
    ushort* __restrict__ X, const int* __restrict__ hdr) {
  const int mode = hdr[0];
  const int b = blockIdx.x;
  const void* src = (b < 2560) ? x1 : x2;
  const size_t off = (size_t)(b < 2560 ? b : b - 2560) * 2048 +
                     (size_t)threadIdx.x * 8;
  ushort* dst = X + ((b < 2560) ? off : off + (size_t)2048 * 2560);
  if (mode) {
    const float* f = (const float*)src;
    float4 a = *(const float4*)&f[off];
    float4 bq = *(const float4*)&f[off + 4];
    ushort4 o0, o1;
    o0.x = f2bf(a.x); o0.y = f2bf(a.y); o0.z = f2bf(a.z); o0.w = f2bf(a.w);
    o1.x = f2bf(bq.x); o1.y = f2bf(bq.y); o1.z = f2bf(bq.z); o1.w = f2bf(bq.w);
    *(ushort4*)dst = o0;
    *(ushort4*)(dst + 4) = o1;
  } else {
    *(uint4*)dst = *(const uint4*)((const ushort*)src + off);
  }
}

// ---- 64x64 transpose, dual-dtype source, bf16 dest: dst[c][r]=src[r][c] ----
__global__ __launch_bounds__(256, 4) void transpose_kernel(
    const void* __restrict__ src_v, ushort* __restrict__ dst, int srcStride,
    int dstStride, long srcBatch, long dstBatch,
    const int* __restrict__ hdr) {
  __shared__ __align__(16) ushort tile[64][68];
  const int mode = hdr[0];
  const size_t sb = (size_t)blockIdx.z * srcBatch;
  ushort* d = dst + (size_t)blockIdx.z * dstBatch;
  const int r0 = blockIdx.x * 64;
  const int c0 = blockIdx.y * 64;
  const int tid = threadIdx.x;
#pragma unroll
  for (int i = 0; i < 4; i++) {
    int e = tid + 256 * i;
    int r = e >> 4;
    int c4 = (e & 15) * 4;
    size_t idx = sb + (size_t)(r0 + r) * srcStride + c0 + c4;
    if (mode) {
      float4 f = *(const float4*)&((const float*)src_v)[idx];
      tile[r][c4 + 0] = f2bf(f.x);
      tile[r][c4 + 1] = f2bf(f.y);
      tile[r][c4 + 2] = f2bf(f.z);
      tile[r][c4 + 3] = f2bf(f.w);
    } else {
      *(ushort4*)&tile[r][c4] = *(const ushort4*)&((const ushort*)src_v)[idx];
    }
  }
  __syncthreads();
#pragma unroll
  for (int i = 0; i < 4; i++) {
    int e = tid + 256 * i;
    int c = e >> 4;
    int r4 = (e & 15) * 4;
    ushort4 v;
    v.x = tile[r4 + 0][c];
    v.y = tile[r4 + 1][c];
    v.z = tile[r4 + 2][c];
    v.w = tile[r4 + 3][c];
    *(ushort4*)&d[(size_t)(c0 + c) * dstStride + r0 + r4] = v;
  }
}

// ---- 128x128 bf16 MFMA GEMM: C = A(MxK) * Bt(NxK)^T; C dtype per hdr ----
__global__ __launch_bounds__(256, 2) void gemm_bt(
    const ushort* __restrict__ A, const ushort* __restrict__ Bt,
    void* __restrict__ C, int Ncols, int Kdim,
    const int* __restrict__ outModePtr) {
  __shared__ __align__(16) ushort lA[128 * 32];
  __shared__ __align__(16) ushort lB[128 * 32];
  const int outMode = outModePtr[0];
  const int tid = threadIdx.x;
  const int wave = tid >> 6;
  const int lane = tid & 63;
  const int quad = lane >> 4;
  const int l16 = lane & 15;
  const long bm = (long)blockIdx.x * 128;
  const long bn = (long)blockIdx.y * 128;
  const int wr = (wave >> 1) * 64;
  const int wc = (wave & 1) * 64;

  f32x4 acc[4][4];
#pragma unroll
  for (int mt = 0; mt < 4; mt++)
#pragma unroll
    for (int nt = 0; nt < 4; nt++) acc[mt][nt] = {0.f, 0.f, 0.f, 0.f};

  const int srow = wave * 32 + (lane >> 2);  // staging row within tile
  const int scol = (lane & 3) * 8;           // staging col (elements)

  for (int k0 = 0; k0 < Kdim; k0 += 32) {
    async_load16(&lA[(wave * 32) * 32],
                 &A[(size_t)(bm + srow) * Kdim + k0 + scol]);
    async_load16(&lA[(wave * 32 + 16) * 32],
                 &A[(size_t)(bm + srow + 16) * Kdim + k0 + scol]);
    async_load16(&lB[(wave * 32) * 32],
                 &Bt[(size_t)(bn + srow) * Kdim + k0 + scol]);
    async_load16(&lB[(wave * 32 + 16) * 32],
                 &Bt[(size_t)(bn + srow + 16) * Kdim + k0 + scol]);
    __syncthreads();
    s16x8 af[4], bf[4];
#pragma unroll
    for (int mt = 0; mt < 4; mt++)
      af[mt] = *(const s16x8*)&lA[(wr + mt * 16 + l16) * 32 + quad * 8];
#pragma unroll
    for (int nt = 0; nt < 4; nt++)
      bf[nt] = *(const s16x8*)&lB[(wc + nt * 16 + l16) * 32 + quad * 8];
#pragma unroll
    for (int mt = 0; mt < 4; mt++)
#pragma unroll
      for (int nt = 0; nt < 4; nt++)
        acc[mt][nt] = __builtin_amdgcn_mfma_f32_16x16x32_bf16(
            as_bf(af[mt]), as_bf(bf[nt]), acc[mt][nt], 0, 0, 0);
    __syncthreads();
  }
#pragma unroll
  for (int mt = 0; mt < 4; mt++)
#pragma unroll
    for (int nt = 0; nt < 4; nt++)
#pragma unroll
      for (int r = 0; r < 4; r++) {
        long row = bm + wr + mt * 16 + quad * 4 + r;
        long col = bn + wc + nt * 16 + l16;
        if (outMode)
          ((float*)C)[row * (long)Ncols + col] = acc[mt][nt][r];
        else
          ((ushort*)C)[row * (long)Ncols + col] = f2bf(acc[mt][nt][r]);
      }
}

// ---------------- fused RMSNorm + RoPE + q-scale, in place -----------------
__global__ __launch_bounds__(256, 4) void normrope_kernel(
    ushort* __restrict__ qkv, const void* __restrict__ qscale,
    const void* __restrict__ kscale, const int* __restrict__ hdr) {
  const int mode = hdr[0];
  const int wave = threadIdx.x >> 6;
  const int lane = threadIdx.x & 63;
  const int vec = blockIdx.x * 4 + wave;  // 0 .. T*(NQ+NKV)-1
  const int t = vec / 12;
  const int head = vec - t * 12;
  const bool isq = head < NQ;
  ushort* base = qkv + (size_t)t * QKV_COLS +
                 (isq ? head * HD : 2048 + (head - NQ) * HD);
  ushort4 raw = *(ushort4*)&base[lane * 4];
  float x[4] = {bf2f(raw.x), bf2f(raw.y), bf2f(raw.z), bf2f(raw.w)};
  float ss = x[0] * x[0] + x[1] * x[1] + x[2] * x[2] + x[3] * x[3];
#pragma unroll
  for (int d = 1; d < 64; d <<= 1) ss += __shfl_xor(ss, d);
  const float inv = rsqrtf(ss * (1.0f / 256.0f) + 1e-6f);
  const void* scp = isq ? qscale : kscale;
  float sc[4];
  if (mode) {
    float4 f = *(const float4*)&((const float*)scp)[lane * 4];
    sc[0] = f.x; sc[1] = f.y; sc[2] = f.z; sc[3] = f.w;
  } else {
    ushort4 u = *(const ushort4*)&((const ushort*)scp)[lane * 4];
    sc[0] = bf2f(u.x); sc[1] = bf2f(u.y); sc[2] = bf2f(u.z); sc[3] = bf2f(u.w);
  }
  float nv[4];
#pragma unroll
  for (int e = 0; e < 4; e++) nv[e] = x[e] * inv * (1.f + sc[e]);
  float other[4];
#pragma unroll
  for (int e = 0; e < 4; e++) other[e] = __shfl_xor(nv[e], 32);
  const float tpos = (float)t;
  const float qsc = isq ? 0.0625f : 1.0f;
  float res[4];
#pragma unroll
  for (int e = 0; e < 4; e++) {
    int i = (lane * 4 + e) & 127;
    // timescale = 10000^(i/128) = exp(ln(10000)*i/128)
    float ts = expf((float)i * (9.210340371976184f / 128.0f));
    float ang = tpos / ts;
    float sn, cs;
    sincosf(ang, &sn, &cs);
    float v = (lane < 32) ? (nv[e] * cs - other[e] * sn)
                          : (nv[e] * cs + other[e] * sn);
    res[e] = v * qsc;
  }
  ushort4 outv;
  outv.x = f2bf(res[0]);
  outv.y = f2bf(res[1]);
  outv.z = f2bf(res[2]);
  outv.w = f2bf(res[3]);
  *(ushort4*)&base[lane * 4] = outv;
}

// ---------------- flash attention, sliding-window causal -------------------
__global__ __launch_bounds__(256, 2) void attn_kernel(
    const ushort* __restrict__ qkv, const ushort* __restrict__ vt,
    ushort* __restrict__ enc) {
  __shared__ __align__(16) ushort Pbuf[4][16 * 32];
  const int wave = threadIdx.x >> 6;
  const int lane = threadIdx.x & 63;
  const int quad = lane >> 4;
  const int l16 = lane & 15;
  const int n = blockIdx.y;
  const int kh = n >> 1;  // G = 2
  const int qt0 = blockIdx.x * 64 + wave * 16;

  // Q fragments (A-layout): 16 queries x 256 h
  s16x8 qf[8];
  {
    const ushort* qp =
        qkv + (size_t)(qt0 + l16) * QKV_COLS + n * HD + quad * 8;
#pragma unroll
    for (int ko = 0; ko < 8; ko++) qf[ko] = *(const s16x8*)(qp + ko * 32);
  }
  float m_i[4], l_i[4];
  f32x4 accv[16];
#pragma unroll
  for (int ht = 0; ht < 16; ht++) accv[ht] = {0.f, 0.f, 0.f, 0.f};
#pragma unroll
  for (int r = 0; r < 4; r++) {
    m_i[r] = -1e30f;
    l_i[r] = 0.f;
  }

  int s_begin = qt0 - (WIN - 1);
  if (s_begin < 0) s_begin = 0;
  s_begin &= ~31;
  const int s_end = qt0 + 16;
  const ushort* kbase = qkv + 2048 + kh * HD + quad * 8;
  const ushort* vtb = vt + (size_t)kh * HD * T_LEN;

  for (int sc = s_begin; sc < s_end; sc += 32) {
    const int sa = sc + l16;
    const int sb = sc + 16 + l16;
    f32x4 lg0 = {0.f, 0.f, 0.f, 0.f};
    f32x4 lg1 = {0.f, 0.f, 0.f, 0.f};
    const ushort* ka = kbase + (size_t)sa * QKV_COLS;
    const ushort* kb = kbase + (size_t)sb * QKV_COLS;
#pragma unroll
    for (int ko = 0; ko < 8; ko++) {
      s16x8 k0v = *(const s16x8*)(ka + ko * 32);
      s16x8 k1v = *(const s16x8*)(kb + ko * 32);
      lg0 = __builtin_amdgcn_mfma_f32_16x16x32_bf16(as_bf(qf[ko]), as_bf(k0v),
                                                    lg0, 0, 0, 0);
      lg1 = __builtin_amdgcn_mfma_f32_16x16x32_bf16(as_bf(qf[ko]), as_bf(k1v),
                                                    lg1, 0, 0, 0);
    }
    float p0[4], p1[4], mx[4], alpha[4], rs[4];
#pragma unroll
    for (int r = 0; r < 4; r++) {
      const int t = qt0 + quad * 4 + r;
      float a = ((sa > t) || (sa < t - (WIN - 1))) ? NEG_BIG : lg0[r];
      float b = ((sb > t) || (sb < t - (WIN - 1))) ? NEG_BIG : lg1[r];
      p0[r] = a;
      p1[r] = b;
      mx[r] = fmaxf(a, b);
    }
#pragma unroll
    for (int d = 1; d < 16; d <<= 1)
#pragma unroll
      for (int r = 0; r < 4; r++) mx[r] = fmaxf(mx[r], __shfl_xor(mx[r], d));
#pragma unroll
    for (int r = 0; r < 4; r++) {
      float mn = fmaxf(m_i[r], mx[r]);  // floored at -1e30: masked-only safe
      alpha[r] = __expf(m_i[r] - mn);
      m_i[r] = mn;
      p0[r] = __expf(p0[r] - mn);
      p1[r] = __expf(p1[r] - mn);
      rs[r] = p0[r] + p1[r];
    }
#pragma unroll
    for (int d = 1; d < 16; d <<= 1)
#pragma unroll
      for (int r = 0; r < 4; r++) rs[r] += __shfl_xor(rs[r], d);
#pragma unroll
    for (int r = 0; r < 4; r++) l_i[r] = l_i[r] * alpha[r] + rs[r];

    // P: C-layout -> A-layout via per-wave LDS round trip
    ushort* P = Pbuf[wave];
#pragma unroll
    for (int r = 0; r < 4; r++) {
      P[(quad * 4 + r) * 32 + l16] = f2bf(p0[r]);
      P[(quad * 4 + r) * 32 + 16 + l16] = f2bf(p1[r]);
    }
    asm volatile("s_waitcnt lgkmcnt(0)" ::: "memory");
    s16x8 pf = *(const s16x8*)&P[l16 * 32 + quad * 8];

#pragma unroll
    for (int ht = 0; ht < 16; ht++)
#pragma unroll
      for (int r = 0; r < 4; r++) accv[ht][r] = accv[ht][r] * alpha[r];

    const ushort* vb = vtb + sc + quad * 8;
#pragma unroll
    for (int ht = 0; ht < 16; ht++) {
      s16x8 vf = *(const s16x8*)(vb + (size_t)(ht * 16 + l16) * T_LEN);
      accv[ht] = __builtin_amdgcn_mfma_f32_16x16x32_bf16(as_bf(pf), as_bf(vf),
                                                         accv[ht], 0, 0, 0);
    }
  }
#pragma unroll
  for (int ht = 0; ht < 16; ht++)
#pragma unroll
    for (int r = 0; r < 4; r++) {
      const int t = qt0 + quad * 4 + r;
      enc[(size_t)t * ENC_COLS + n * HD + ht * 16 + l16] =
          f2bf(accv[ht][r] / l_i[r]);
    }
}

extern "C" void kernel_launch(void* const* d_in, const int* in_sizes, int n_in,
                              void* d_out, int out_size, void* d_ws,
                              size_t ws_size, hipStream_t stream) {
  (void)in_sizes; (void)n_in; (void)out_size; (void)ws_size;
  const void* x1 = d_in[0];
  const void* x2 = d_in[1];
  const void* q_w = d_in[2];
  const void* kv_w = d_in[3];
  const void* out_w = d_in[4];
  const void* q_ns = d_in[5];
  const void* k_ns = d_in[6];

  // ws layout (62,914,816 B total):
  //   hdr @ 0            : 256 B (mode flag; hdr[1] hardwired 0)
  //   X   @ 256          : 4096 x 2560 bf16 (20,971,520 B)  [dead after GEMM1]
  //   QKV @ 20,971,776   : 4096 x 4096 bf16 (33,554,432 B)  [dead after attn]
  //   Vt  @ 54,526,208   : 4 x 256 x 4096 bf16 (8,388,608 B)
  //   ENC aliases X @ 256 (16,777,216 B)
  //   BtOut aliases QKV @ 20,971,776 (10,485,760 B) -- written after attn
  // d_out doubles as BtQKV (4096 x 2560 bf16 = 20.97 MB; d_out is >= that in
  // either output-dtype mode) until GEMM1 consumes it.
  char* ws = (char*)d_ws;
  int* hdr = (int*)ws;
  ushort* X = (ushort*)(ws + 256);
  ushort* QKV = (ushort*)(ws + 20971776);
  ushort* Vt = (ushort*)(ws + 54526208);
  ushort* ENC = (ushort*)(ws + 256);
  ushort* BtOut = (ushort*)(ws + 20971776);
  ushort* BtQKV = (ushort*)d_out;

  detect_kernel<<<1, 256, 0, stream>>>((const ushort*)x1, hdr);

  // x1/x2 -> canonical bf16 X
  convert_x_kernel<<<5120, 256, 0, stream>>>(x1, x2, X, hdr);

  // q_w (N,D,H): per head (2560,256) -> BtQKV rows n*256..  (batch = head)
  transpose_kernel<<<dim3(40, 4, 8), 256, 0, stream>>>(q_w, BtQKV, 256, 2560,
                                                       655360, 655360, hdr);
  // kv_w (2,K,D,H): per (c,kh) (2560,256) -> BtQKV rows 2048 + z*256..
  transpose_kernel<<<dim3(40, 4, 8), 256, 0, stream>>>(
      kv_w, BtQKV + (size_t)2048 * 2560, 256, 2560, 655360, 655360, hdr);

  // QKV = X (4096x2560) * BtQKV^T -> (4096 x 4096) [q | k | v], bf16 out
  gemm_bt<<<dim3(32, 32), 256, 0, stream>>>(X, BtQKV, QKV, 4096, 2560,
                                            hdr + 1);

  // RMSNorm + RoPE on q,k (in place); v untouched
  normrope_kernel<<<12288, 256, 0, stream>>>(QKV, q_ns, k_ns, hdr);

  // V (cols 3072..4096 of QKV, per kh) -> Vt[kh][h][s]  (bf16 source path)
  transpose_kernel<<<dim3(64, 4, 4), 256, 0, stream>>>(QKV + 3072, Vt, 4096,
                                                       4096, 256, 1048576,
                                                       hdr + 1);

  // flash attention -> ENC (4096 x 2048); X is dead by now
  attn_kernel<<<dim3(64, 8), 256, 0, stream>>>(QKV, Vt, ENC);

  // out_w flat (2048,2560) -> BtOut (2560,2048); QKV region dead now
  transpose_kernel<<<dim3(32, 40, 1), 256, 0, stream>>>(out_w, BtOut, 2560,
                                                        2048, 0, 0, hdr);

  // out = ENC (4096x2048) * BtOut^T -> (4096 x 2560) in output dtype
  gemm_bt<<<dim3(32, 20), 256, 0, stream>>>(ENC, BtOut, d_out, 2560, 2048,
                                            hdr);
}

// Round 4
// 470.827 us; speedup vs baseline: 1.3006x; 1.3006x over previous
//
#include <hip/hip_runtime.h>
#include <stdint.h>

#define T_LEN 4096
#define D_DIM 2560
#define NQ 8
#define NKV 4
#define HD 256
#define QKV_COLS 4096
#define ENC_COLS 2048
#define WIN 1024
#define NEG_BIG -3.0e38f

typedef __bf16 bf16x8 __attribute__((ext_vector_type(8)));
typedef short s16x8 __attribute__((ext_vector_type(8)));
typedef float f32x4 __attribute__((ext_vector_type(4)));

__device__ __forceinline__ float bf2f(ushort u) {
  union { unsigned u; float f; } v; v.u = ((unsigned)u) << 16; return v.f;
}
__device__ __forceinline__ ushort f2bf(float f) {
  union { float f; unsigned u; } v; v.f = f;
  unsigned r = v.u + 0x7fffu + ((v.u >> 16) & 1u);
  return (ushort)(r >> 16);
}
__device__ __forceinline__ bf16x8 as_bf(s16x8 s) {
  return __builtin_bit_cast(bf16x8, s);
}
__device__ __forceinline__ void async_load16(void* lds, const void* g) {
  __builtin_amdgcn_global_load_lds(
      (const __attribute__((address_space(1))) void*)g,
      (__attribute__((address_space(3))) void*)lds, 16, 0, 0);
}

// ---- dtype probe: bf16 N(0,1) never has exponent >= 192; fp32 low halves
// ---- read as bf16 hit that ~25% of the time. hdr[0]=mode, hdr[1]=0.
__global__ void detect_kernel(const ushort* __restrict__ x1, int* hdr) {
  __shared__ int cnt;
  if (threadIdx.x == 0) cnt = 0;
  __syncthreads();
  int c = 0;
#pragma unroll
  for (int i = 0; i < 8; i++) {
    ushort u = x1[threadIdx.x * 8 + i];
    c += (((u >> 7) & 0xFF) >= 192) ? 1 : 0;
  }
  atomicAdd(&cnt, c);
  __syncthreads();
  if (threadIdx.x == 0) {
    hdr[0] = (cnt > 32) ? 1 : 0;
    hdr[1] = 0;
  }
}

// ---- x1/x2 -> canonical bf16 X (4096 x 2560). 2560 blocks per half. ----
__global__ __launch_bounds__(256, 4) void convert_x_kernel(
    const void* __restrict__ x1, const void* __restrict__ x2,
    ushort* __restrict__ X, const int* __restrict__ hdr) {
  const int mode = hdr[0];
  const int b = blockIdx.x;
  const void* src = (b < 2560) ? x1 : x2;
  const size_t off = (size_t)(b < 2560 ? b : b - 2560) * 2048 +
                     (size_t)threadIdx.x * 8;
  ushort* dst = X + ((b < 2560) ? off : off + (size_t)2048 * 2560);
  if (mode) {
    const float* f = (const float*)src;
    float4 a = *(const float4*)&f[off];
    float4 bq = *(const float4*)&f[off + 4];
    ushort4 o0, o1;
    o0.x = f2bf(a.x); o0.y = f2bf(a.y); o0.z = f2bf(a.z); o0.w = f2bf(a.w);
    o1.x = f2bf(bq.x); o1.y = f2bf(bq.y); o1.z = f2bf(bq.z); o1.w = f2bf(bq.w);
    *(ushort4*)dst = o0;
    *(ushort4*)(dst + 4) = o1;
  } else {
    *(uint4*)dst = *(const uint4*)((const ushort*)src + off);
  }
}

// ---- 64x64 transpose, dual-dtype source, bf16 dest: dst[c][r]=src[r][c] ----
__global__ __launch_bounds__(256, 4) void transpose_kernel(
    const void* __restrict__ src_v, ushort* __restrict__ dst, int srcStride,
    int dstStride, long srcBatch, long dstBatch,
    const int* __restrict__ hdr) {
  __shared__ __align__(16) ushort tile[64][68];
  const int mode = hdr[0];
  const size_t sb = (size_t)blockIdx.z * srcBatch;
  ushort* d = dst + (size_t)blockIdx.z * dstBatch;
  const int r0 = blockIdx.x * 64;
  const int c0 = blockIdx.y * 64;
  const int tid = threadIdx.x;
#pragma unroll
  for (int i = 0; i < 4; i++) {
    int e = tid + 256 * i;
    int r = e >> 4;
    int c4 = (e & 15) * 4;
    size_t idx = sb + (size_t)(r0 + r) * srcStride + c0 + c4;
    if (mode) {
      float4 f = *(const float4*)&((const float*)src_v)[idx];
      tile[r][c4 + 0] = f2bf(f.x);
      tile[r][c4 + 1] = f2bf(f.y);
      tile[r][c4 + 2] = f2bf(f.z);
      tile[r][c4 + 3] = f2bf(f.w);
    } else {
      *(ushort4*)&tile[r][c4] = *(const ushort4*)&((const ushort*)src_v)[idx];
    }
  }
  __syncthreads();
#pragma unroll
  for (int i = 0; i < 4; i++) {
    int e = tid + 256 * i;
    int c = e >> 4;
    int r4 = (e & 15) * 4;
    ushort4 v;
    v.x = tile[r4 + 0][c];
    v.y = tile[r4 + 1][c];
    v.z = tile[r4 + 2][c];
    v.w = tile[r4 + 3][c];
    *(ushort4*)&d[(size_t)(c0 + c) * dstStride + r0 + r4] = v;
  }
}

// ---- 128x128 bf16 MFMA GEMM: C = A(MxK) * Bt(NxK)^T; C dtype per hdr ----
__global__ __launch_bounds__(256, 2) void gemm_bt(
    const ushort* __restrict__ A, const ushort* __restrict__ Bt,
    void* __restrict__ C, int Ncols, int Kdim,
    const int* __restrict__ outModePtr) {
  __shared__ __align__(16) ushort lA[128 * 32];
  __shared__ __align__(16) ushort lB[128 * 32];
  const int outMode = outModePtr[0];
  const int tid = threadIdx.x;
  const int wave = tid >> 6;
  const int lane = tid & 63;
  const int quad = lane >> 4;
  const int l16 = lane & 15;
  const long bm = (long)blockIdx.x * 128;
  const long bn = (long)blockIdx.y * 128;
  const int wr = (wave >> 1) * 64;
  const int wc = (wave & 1) * 64;

  f32x4 acc[4][4];
#pragma unroll
  for (int mt = 0; mt < 4; mt++)
#pragma unroll
    for (int nt = 0; nt < 4; nt++) acc[mt][nt] = {0.f, 0.f, 0.f, 0.f};

  const int srow = wave * 32 + (lane >> 2);  // staging row within tile
  const int scol = (lane & 3) * 8;           // staging col (elements)

  for (int k0 = 0; k0 < Kdim; k0 += 32) {
    async_load16(&lA[(wave * 32) * 32],
                 &A[(size_t)(bm + srow) * Kdim + k0 + scol]);
    async_load16(&lA[(wave * 32 + 16) * 32],
                 &A[(size_t)(bm + srow + 16) * Kdim + k0 + scol]);
    async_load16(&lB[(wave * 32) * 32],
                 &Bt[(size_t)(bn + srow) * Kdim + k0 + scol]);
    async_load16(&lB[(wave * 32 + 16) * 32],
                 &Bt[(size_t)(bn + srow + 16) * Kdim + k0 + scol]);
    __syncthreads();
    s16x8 af[4], bf[4];
#pragma unroll
    for (int mt = 0; mt < 4; mt++)
      af[mt] = *(const s16x8*)&lA[(wr + mt * 16 + l16) * 32 + quad * 8];
#pragma unroll
    for (int nt = 0; nt < 4; nt++)
      bf[nt] = *(const s16x8*)&lB[(wc + nt * 16 + l16) * 32 + quad * 8];
#pragma unroll
    for (int mt = 0; mt < 4; mt++)
#pragma unroll
      for (int nt = 0; nt < 4; nt++)
        acc[mt][nt] = __builtin_amdgcn_mfma_f32_16x16x32_bf16(
            as_bf(af[mt]), as_bf(bf[nt]), acc[mt][nt], 0, 0, 0);
    __syncthreads();
  }
#pragma unroll
  for (int mt = 0; mt < 4; mt++)
#pragma unroll
    for (int nt = 0; nt < 4; nt++)
#pragma unroll
      for (int r = 0; r < 4; r++) {
        long row = bm + wr + mt * 16 + quad * 4 + r;
        long col = bn + wc + nt * 16 + l16;
        if (outMode)
          ((float*)C)[row * (long)Ncols + col] = acc[mt][nt][r];
        else
          ((ushort*)C)[row * (long)Ncols + col] = f2bf(acc[mt][nt][r]);
      }
}

// ---------------- fused RMSNorm + RoPE + q-scale, in place -----------------
__global__ __launch_bounds__(256, 4) void normrope_kernel(
    ushort* __restrict__ qkv, const void* __restrict__ qscale,
    const void* __restrict__ kscale, const int* __restrict__ hdr) {
  const int mode = hdr[0];
  const int wave = threadIdx.x >> 6;
  const int lane = threadIdx.x & 63;
  const int vec = blockIdx.x * 4 + wave;  // 0 .. T*(NQ+NKV)-1
  const int t = vec / 12;
  const int head = vec - t * 12;
  const bool isq = head < NQ;
  ushort* base = qkv + (size_t)t * QKV_COLS +
                 (isq ? head * HD : 2048 + (head - NQ) * HD);
  ushort4 raw = *(ushort4*)&base[lane * 4];
  float x[4] = {bf2f(raw.x), bf2f(raw.y), bf2f(raw.z), bf2f(raw.w)};
  float ss = x[0] * x[0] + x[1] * x[1] + x[2] * x[2] + x[3] * x[3];
#pragma unroll
  for (int d = 1; d < 64; d <<= 1) ss += __shfl_xor(ss, d);
  const float inv = rsqrtf(ss * (1.0f / 256.0f) + 1e-6f);
  const void* scp = isq ? qscale : kscale;
  float sc[4];
  if (mode) {
    float4 f = *(const float4*)&((const float*)scp)[lane * 4];
    sc[0] = f.x; sc[1] = f.y; sc[2] = f.z; sc[3] = f.w;
  } else {
    ushort4 u = *(const ushort4*)&((const ushort*)scp)[lane * 4];
    sc[0] = bf2f(u.x); sc[1] = bf2f(u.y); sc[2] = bf2f(u.z); sc[3] = bf2f(u.w);
  }
  float nv[4];
#pragma unroll
  for (int e = 0; e < 4; e++) nv[e] = x[e] * inv * (1.f + sc[e]);
  float other[4];
#pragma unroll
  for (int e = 0; e < 4; e++) other[e] = __shfl_xor(nv[e], 32);
  const float tpos = (float)t;
  const float qsc = isq ? 0.0625f : 1.0f;
  float res[4];
#pragma unroll
  for (int e = 0; e < 4; e++) {
    int i = (lane * 4 + e) & 127;
    // timescale = 10000^(i/128) = exp(ln(10000)*i/128)
    float ts = expf((float)i * (9.210340371976184f / 128.0f));
    float ang = tpos / ts;
    float sn, cs;
    sincosf(ang, &sn, &cs);
    float v = (lane < 32) ? (nv[e] * cs - other[e] * sn)
                          : (nv[e] * cs + other[e] * sn);
    res[e] = v * qsc;
  }
  ushort4 outv;
  outv.x = f2bf(res[0]);
  outv.y = f2bf(res[1]);
  outv.z = f2bf(res[2]);
  outv.w = f2bf(res[3]);
  *(ushort4*)&base[lane * 4] = outv;
}

// -------- flash attention, sliding-window causal, LDS-staged K/V -----------
// Block: 4 waves, 64 queries (16/wave), one q-head. K/V chunks of 32 keys
// double-buffered in LDS via global_load_lds(16B), XOR-swizzled so fragment
// ds_read_b128s are (near) bank-conflict-free.
__global__ __launch_bounds__(256, 2) void attn_kernel(
    const ushort* __restrict__ qkv, const ushort* __restrict__ vt,
    ushort* __restrict__ enc) {
  __shared__ __align__(16) ushort Kbuf[2][32 * 256];  // 16 KB each
  __shared__ __align__(16) ushort Vbuf[2][256 * 32];  // 16 KB each
  __shared__ __align__(16) ushort Pbuf[4][16 * 32];
  const int wave = threadIdx.x >> 6;
  const int lane = threadIdx.x & 63;
  const int quad = lane >> 4;
  const int l16 = lane & 15;
  const int n = blockIdx.y;
  const int kh = n >> 1;  // G = 2
  const int qt_blk = blockIdx.x * 64;
  const int qt0 = qt_blk + wave * 16;

  // Q fragments (A-layout): 16 queries x 256 h
  s16x8 qf[8];
  {
    const ushort* qp =
        qkv + (size_t)(qt0 + l16) * QKV_COLS + n * HD + quad * 8;
#pragma unroll
    for (int ko = 0; ko < 8; ko++) qf[ko] = *(const s16x8*)(qp + ko * 32);
  }
  float m_i[4], l_i[4];
  f32x4 accv[16];
#pragma unroll
  for (int ht = 0; ht < 16; ht++) accv[ht] = {0.f, 0.f, 0.f, 0.f};
#pragma unroll
  for (int r = 0; r < 4; r++) {
    m_i[r] = -1e30f;
    l_i[r] = 0.f;
  }

  int s_lo = qt_blk - (WIN - 1);
  if (s_lo < 0) s_lo = 0;
  s_lo &= ~31;
  const int nch = (qt_blk + 64 - s_lo) >> 5;

  const ushort* kgbase = qkv + 2048 + kh * HD;
  const ushort* vgbase = vt + (size_t)kh * HD * T_LEN;

  // staging: wave stages K rows [wave*8, wave*8+8) and Vt rows [wave*64, +64)
  const int kr_off = (lane >> 5);        // 0..1 (2 K rows per issue)
  const int kc = lane & 31;              // 16B chunk within 512B K row
  const int vr_off = (lane >> 2);        // 0..15 (16 V rows per issue)
  const int vc = lane & 3;               // 16B chunk within 64B V row

#define STAGE_CHUNK(buf, sc_)                                              \
  {                                                                        \
    const int sc__ = (sc_);                                                \
    _Pragma("unroll") for (int j = 0; j < 4; j++) {                        \
      const int kr = wave * 8 + j * 2 + kr_off;                            \
      const int kcs = kc ^ (kr & 7);                                       \
      async_load16(&Kbuf[buf][(wave * 8 + j * 2) * 256],                   \
                   kgbase + (size_t)(sc__ + kr) * QKV_COLS + kcs * 8);     \
      const int vr = wave * 64 + j * 16 + vr_off;                          \
      const int vcs = vc ^ (vr & 3);                                       \
      async_load16(&Vbuf[buf][(wave * 64 + j * 16) * 32],                  \
                   vgbase + (size_t)vr * T_LEN + sc__ + vcs * 8);          \
    }                                                                      \
  }

  STAGE_CHUNK(0, s_lo);

  for (int ci = 0; ci < nch; ci++) {
    const int b = ci & 1;
    const int sc = s_lo + ci * 32;
    __syncthreads();  // staging of buf b complete; buf 1-b free for reuse
    if (ci + 1 < nch) STAGE_CHUNK(1 - b, sc + 32);

    // wave-level skip: chunk entirely outside this wave's window
    if (sc > qt0 + 15 || sc + 31 < qt0 + 15 - (WIN - 1)) continue;

    f32x4 lg0 = {0.f, 0.f, 0.f, 0.f};
    f32x4 lg1 = {0.f, 0.f, 0.f, 0.f};
#pragma unroll
    for (int ko = 0; ko < 8; ko++) {
      const int cc = ko * 4 + quad;
      s16x8 k0v = *(const s16x8*)&Kbuf[b][l16 * 256 + (cc ^ (l16 & 7)) * 8];
      s16x8 k1v =
          *(const s16x8*)&Kbuf[b][(16 + l16) * 256 + (cc ^ (l16 & 7)) * 8];
      lg0 = __builtin_amdgcn_mfma_f32_16x16x32_bf16(as_bf(qf[ko]), as_bf(k0v),
                                                    lg0, 0, 0, 0);
      lg1 = __builtin_amdgcn_mfma_f32_16x16x32_bf16(as_bf(qf[ko]), as_bf(k1v),
                                                    lg1, 0, 0, 0);
    }
    const int sa = sc + l16;
    const int sb = sc + 16 + l16;
    float p0[4], p1[4], mx[4], alpha[4], rs[4];
#pragma unroll
    for (int r = 0; r < 4; r++) {
      const int t = qt0 + quad * 4 + r;
      float a = ((sa > t) || (sa < t - (WIN - 1))) ? NEG_BIG : lg0[r];
      float bq = ((sb > t) || (sb < t - (WIN - 1))) ? NEG_BIG : lg1[r];
      p0[r] = a;
      p1[r] = bq;
      mx[r] = fmaxf(a, bq);
    }
#pragma unroll
    for (int d = 1; d < 16; d <<= 1)
#pragma unroll
      for (int r = 0; r < 4; r++) mx[r] = fmaxf(mx[r], __shfl_xor(mx[r], d));
#pragma unroll
    for (int r = 0; r < 4; r++) {
      float mn = fmaxf(m_i[r], mx[r]);  // floored at -1e30: masked-only safe
      alpha[r] = __expf(m_i[r] - mn);
      m_i[r] = mn;
      p0[r] = __expf(p0[r] - mn);
      p1[r] = __expf(p1[r] - mn);
      rs[r] = p0[r] + p1[r];
    }
#pragma unroll
    for (int d = 1; d < 16; d <<= 1)
#pragma unroll
      for (int r = 0; r < 4; r++) rs[r] += __shfl_xor(rs[r], d);
#pragma unroll
    for (int r = 0; r < 4; r++) l_i[r] = l_i[r] * alpha[r] + rs[r];

    // P: C-layout -> A-layout via per-wave LDS round trip
    ushort* P = Pbuf[wave];
#pragma unroll
    for (int r = 0; r < 4; r++) {
      P[(quad * 4 + r) * 32 + l16] = f2bf(p0[r]);
      P[(quad * 4 + r) * 32 + 16 + l16] = f2bf(p1[r]);
    }
    asm volatile("s_waitcnt lgkmcnt(0)" ::: "memory");
    s16x8 pf = *(const s16x8*)&P[l16 * 32 + quad * 8];

#pragma unroll
    for (int ht = 0; ht < 16; ht++)
#pragma unroll
      for (int r = 0; r < 4; r++) accv[ht][r] = accv[ht][r] * alpha[r];

#pragma unroll
    for (int ht = 0; ht < 16; ht++) {
      const int vr = ht * 16 + l16;
      s16x8 vf =
          *(const s16x8*)&Vbuf[b][vr * 32 + ((quad ^ (vr & 3)) * 8)];
      accv[ht] = __builtin_amdgcn_mfma_f32_16x16x32_bf16(as_bf(pf), as_bf(vf),
                                                         accv[ht], 0, 0, 0);
    }
  }
#pragma unroll
  for (int ht = 0; ht < 16; ht++)
#pragma unroll
    for (int r = 0; r < 4; r++) {
      const int t = qt0 + quad * 4 + r;
      enc[(size_t)t * ENC_COLS + n * HD + ht * 16 + l16] =
          f2bf(accv[ht][r] / l_i[r]);
    }
}

extern "C" void kernel_launch(void* const* d_in, const int* in_sizes, int n_in,
                              void* d_out, int out_size, void* d_ws,
                              size_t ws_size, hipStream_t stream) {
  (void)in_sizes; (void)n_in; (void)out_size; (void)ws_size;
  const void* x1 = d_in[0];
  const void* x2 = d_in[1];
  const void* q_w = d_in[2];
  const void* kv_w = d_in[3];
  const void* out_w = d_in[4];
  const void* q_ns = d_in[5];
  const void* k_ns = d_in[6];

  // ws layout (62,914,816 B total):
  //   hdr @ 0            : 256 B (mode flag; hdr[1] hardwired 0)
  //   X   @ 256          : 4096 x 2560 bf16 (20,971,520 B)  [dead after GEMM1]
  //   QKV @ 20,971,776   : 4096 x 4096 bf16 (33,554,432 B)  [dead after attn]
  //   Vt  @ 54,526,208   : 4 x 256 x 4096 bf16 (8,388,608 B)
  //   ENC aliases X @ 256 (16,777,216 B)
  //   BtOut aliases QKV @ 20,971,776 (10,485,760 B) -- written after attn
  // d_out doubles as BtQKV (4096 x 2560 bf16 = 20.97 MB; d_out is >= that in
  // either output-dtype mode) until GEMM1 consumes it.
  char* ws = (char*)d_ws;
  int* hdr = (int*)ws;
  ushort* X = (ushort*)(ws + 256);
  ushort* QKV = (ushort*)(ws + 20971776);
  ushort* Vt = (ushort*)(ws + 54526208);
  ushort* ENC = (ushort*)(ws + 256);
  ushort* BtOut = (ushort*)(ws + 20971776);
  ushort* BtQKV = (ushort*)d_out;

  detect_kernel<<<1, 256, 0, stream>>>((const ushort*)x1, hdr);

  // x1/x2 -> canonical bf16 X
  convert_x_kernel<<<5120, 256, 0, stream>>>(x1, x2, X, hdr);

  // q_w (N,D,H): per head (2560,256) -> BtQKV rows n*256..  (batch = head)
  transpose_kernel<<<dim3(40, 4, 8), 256, 0, stream>>>(q_w, BtQKV, 256, 2560,
                                                       655360, 655360, hdr);
  // kv_w (2,K,D,H): per (c,kh) (2560,256) -> BtQKV rows 2048 + z*256..
  transpose_kernel<<<dim3(40, 4, 8), 256, 0, stream>>>(
      kv_w, BtQKV + (size_t)2048 * 2560, 256, 2560, 655360, 655360, hdr);

  // QKV = X (4096x2560) * BtQKV^T -> (4096 x 4096) [q | k | v], bf16 out
  gemm_bt<<<dim3(32, 32), 256, 0, stream>>>(X, BtQKV, QKV, 4096, 2560,
                                            hdr + 1);

  // RMSNorm + RoPE on q,k (in place); v untouched
  normrope_kernel<<<12288, 256, 0, stream>>>(QKV, q_ns, k_ns, hdr);

  // V (cols 3072..4096 of QKV, per kh) -> Vt[kh][h][s]  (bf16 source path)
  transpose_kernel<<<dim3(64, 4, 4), 256, 0, stream>>>(QKV + 3072, Vt, 4096,
                                                       4096, 256, 1048576,
                                                       hdr + 1);

  // flash attention -> ENC (4096 x 2048); X is dead by now
  attn_kernel<<<dim3(64, 8), 256, 0, stream>>>(QKV, Vt, ENC);

  // out_w flat (2048,2560) -> BtOut (2560,2048); QKV region dead now
  transpose_kernel<<<dim3(32, 40, 1), 256, 0, stream>>>(out_w, BtOut, 2560,
                                                        2048, 0, 0, hdr);

  // out = ENC (4096x2048) * BtOut^T -> (4096 x 2560) in output dtype
  gemm_bt<<<dim3(32, 20), 256, 0, stream>>>(ENC, BtOut, d_out, 2560, 2048,
                                            hdr);
}